// Round 2
// baseline (229.793 us; speedup 1.0000x reference)
//
#include <hip/hip_runtime.h>
#include <cstdint>
#include <cstddef>

#define EPSF 1e-6f

typedef __attribute__((ext_vector_type(4))) float f32x4;
typedef __attribute__((ext_vector_type(8))) short s16x8;
typedef union { s16x8 v; unsigned u[4]; } s16x8u;

// hi/lo dual-bf16 pack via v_cvt_pk_bf16_f32 (1 inst packs 2 floats).
// Residual is computed against the EXACT decode (bf16<<16), so any rounding
// mode in cvt_pk is absorbed by the lo term.
static __device__ __forceinline__ void pack2(float a, float b, unsigned& H, unsigned& L) {
    unsigned h, l;
    asm("v_cvt_pk_bf16_f32 %0, %1, %2" : "=v"(h) : "v"(a), "v"(b));
    float ra = a - __uint_as_float(h << 16);
    float rb = b - __uint_as_float(h & 0xffff0000u);
    asm("v_cvt_pk_bf16_f32 %0, %1, %2" : "=v"(l) : "v"(ra), "v"(rb));
    H = h; L = l;
}
static __device__ __forceinline__ unsigned packH(float a, float b) {
    unsigned h;
    asm("v_cvt_pk_bf16_f32 %0, %1, %2" : "=v"(h) : "v"(a), "v"(b));
    return h;
}

// ws layout (4B units):
//   [0    ..  575]  w1n branch0: [c][9] normalized taps (fp32)
//   [576  .. 1151]  w1n branch1
//   [1152 .. 5247]  w2H branch0 [128][32] u32 c-pair hi
//   [5248 .. 9343]  w2L branch0 [128][32] u32 c-pair lo
//   [9344 ..13439]  w2H branch1
//   [13440..17535]  w2L branch1

// Single merged prep kernel, grid 19 x 256. Every block redundantly computes
// the reductions it needs (t1, t2, per-row sums) in-block.
__global__ __launch_bounds__(256) void prep(const float* __restrict__ w1,
                                            const float* __restrict__ w2,
                                            float* __restrict__ ws) {
    __shared__ float s1row[64];
    __shared__ float red[4];
    __shared__ float rs8[8];
    const int t = threadIdx.x;
    const int lane = t & 63;
    const int wv = t >> 6;
    const int gid = blockIdx.x * 256 + t;

    // t2 = sum over all 8192 w2^2
    float s = 0.f;
    #pragma unroll
    for (int i = 0; i < 32; ++i) { float v = w2[t + 256 * i]; s += v * v; }
    #pragma unroll
    for (int d = 32; d > 0; d >>= 1) s += __shfl_xor(s, d);
    if (lane == 0) red[wv] = s;

    // w1 row sums (64 rows x 9 taps)
    if (t < 64) {
        float rs = 0.f;
        #pragma unroll
        for (int k = 0; k < 9; ++k) { float v = w1[t * 9 + k]; rs += v * v; }
        s1row[t] = rs;
    }

    // per-row w2 sums for the 8 rows this block packs (blocks 0..15 only)
    if (blockIdx.x < 16) {
        const int r8 = t >> 5;            // 0..7
        const int e = t & 31;
        const int row = blockIdx.x * 8 + r8;
        float v0 = w2[row * 64 + e];
        float v1 = w2[row * 64 + 32 + e];
        float rr = v0 * v0 + v1 * v1;
        #pragma unroll
        for (int d = 16; d > 0; d >>= 1) rr += __shfl_down(rr, d);
        if (e == 0) rs8[r8] = rr;
    }
    __syncthreads();

    const float t2 = red[0] + red[1] + red[2] + red[3];
    float a = s1row[lane];
    #pragma unroll
    for (int d = 32; d > 0; d >>= 1) a += __shfl_xor(a, d);
    const float t1 = a;

    unsigned* wsu = (unsigned*)ws;
    if (gid < 4096) {
        const int row = gid >> 5;
        const int cp = gid & 31;
        float v0 = w2[row * 64 + 2 * cp];
        float v1 = w2[row * 64 + 2 * cp + 1];
        float q0 = v0 * v0, q1 = v1 * v1;
        const float rs = rs8[t >> 5];
        unsigned H, L;
        pack2(q0 / t2, q1 / t2, H, L);
        wsu[1152 + row * 32 + cp] = H;
        wsu[5248 + row * 32 + cp] = L;
        pack2(q0 / rs, q1 / rs, H, L);
        wsu[9344 + row * 32 + cp] = H;
        wsu[13440 + row * 32 + cp] = L;
    } else if (gid < 4672) {
        const int i = gid - 4096;
        const int c = i / 9;
        const int k = i - c * 9;
        float v = w1[i];
        float q = v * v;
        ws[c * 9 + k] = q / t1;
        ws[576 + c * 9 + k] = q / s1row[c];
    }
}

// grid: (32, 2, 8)  block: 512 (8 waves), __launch_bounds__(512,4) -> VGPR<=128
// -> exactly 2 resident blocks/CU, 512 blocks = zero occupancy-round tail.
// Each block processes 4 hg-tiles (hg = z + 8i): tile i+1's global x loads are
// issued right after tile i's tap-FMAs, so HBM latency hides under
// pack + barrier + MFMA + epilogue (near-continuous load duty cycle).
// A-fragments (w2) and taps (w1n) are loaded ONCE per block.
// Branch 0 (rot): single bf16 term (outputs O(1e-4), abs err ~2e-7).
// Branch 1 (abs/exp): 3-term hi/lo split (AhBh + AhBl + AlBh).
// Phase 2 is mt-split (acc 16 VGPR live instead of 32) to stay under the cap;
// costs 8 extra ds_read_b128/tile/wave.
__global__ __launch_bounds__(512, 4) void conv_fused(const float* __restrict__ x,
                                                     const float* __restrict__ ws,
                                                     float* __restrict__ out) {
    const int b = blockIdx.x;
    const int branch = blockIdx.y;
    const int z = blockIdx.z;              // 0..7
    const int t = threadIdx.x;
    const int lane = t & 63;
    const int w = __builtin_amdgcn_readfirstlane(t >> 6);
    const int lm = lane & 15;
    const int q = lane >> 4;
    const bool dual = (branch != 0);
    const int T = (z == 7) ? 3 : 4;        // hg = z+8i covers 0..30 exactly once

    __shared__ unsigned rotH[128 * 33];
    __shared__ unsigned rotL[128 * 33];

    const float* __restrict__ w1n = ws + branch * 576;
    const unsigned* __restrict__ wsu = (const unsigned*)ws;
    const unsigned* __restrict__ w2H = wsu + 1152 + branch * 8192;
    const unsigned* __restrict__ w2L = w2H + 4096;
    const float* __restrict__ xb = x + (size_t)(b * 2 + branch) * (64 * 4096);

    const int woc = (w & 3) * 32;
    const int half = w >> 2;
    const int cpair = w * 4 + q;
    const int c0 = 2 * cpair;
    const float* xp0 = xb + c0 * 4096 + 4 * lm;   // + h0*64 (+4096 for ch1)

    // ---- prologue: tile-0 x loads (only exposed latency in the block) ----
    float4 va[4], vb[4];
    {
        const float* p0 = xp0 + (z * 2) * 64;
        #pragma unroll
        for (int r = 0; r < 4; ++r) va[r] = *(const float4*)(p0 + r * 64);
        #pragma unroll
        for (int r = 0; r < 4; ++r) vb[r] = *(const float4*)(p0 + 4096 + r * 64);
    }

    // ---- A fragments: loaded once, resident across all tiles ----
    s16x8u aH[2][2], aL[2][2];
    #pragma unroll
    for (int mt = 0; mt < 2; ++mt) {
        #pragma unroll
        for (int kk = 0; kk < 2; ++kk) {
            const int off = (woc + mt * 16 + lm) * 32 + kk * 16 + q * 4;
            #pragma unroll
            for (int j = 0; j < 4; ++j) aH[mt][kk].u[j] = w2H[off + j];
        }
    }
    if (dual) {
        #pragma unroll
        for (int mt = 0; mt < 2; ++mt) {
            #pragma unroll
            for (int kk = 0; kk < 2; ++kk) {
                const int off = (woc + mt * 16 + lm) * 32 + kk * 16 + q * 4;
                #pragma unroll
                for (int j = 0; j < 4; ++j) aL[mt][kk].u[j] = w2L[off + j];
            }
        }
    }

    // ---- taps: loaded once, resident ----
    float wt0[9], wt1[9];
    {
        const float* wc0 = w1n + c0 * 9;
        #pragma unroll
        for (int k = 0; k < 9; ++k) wt0[k] = wc0[k];
        #pragma unroll
        for (int k = 0; k < 9; ++k) wt1[k] = wc0[9 + k];
    }

    #pragma unroll
    for (int i = 0; i < 4; ++i) {
        if (i < T) {
            const int hg = z + 8 * i;
            const int h0 = hg * 2;

            // ---- phase 1: depthwise 3x3 on 2 channels, 2 output rows ----
            if (dual) {
                #pragma unroll
                for (int r = 0; r < 4; ++r) {
                    va[r].x = __logf(va[r].x + EPSF); va[r].y = __logf(va[r].y + EPSF);
                    va[r].z = __logf(va[r].z + EPSF); va[r].w = __logf(va[r].w + EPSF);
                    vb[r].x = __logf(vb[r].x + EPSF); vb[r].y = __logf(vb[r].y + EPSF);
                    vb[r].z = __logf(vb[r].z + EPSF); vb[r].w = __logf(vb[r].w + EPSF);
                }
            }
            float sax[4], say[4], sbx[4], sby[4];
            #pragma unroll
            for (int r = 0; r < 4; ++r) {
                sax[r] = __shfl_down(va[r].x, 1); say[r] = __shfl_down(va[r].y, 1);
                sbx[r] = __shfl_down(vb[r].x, 1); sby[r] = __shfl_down(vb[r].y, 1);
            }
            float pa[2][4], pb[2][4];
            #pragma unroll
            for (int row = 0; row < 2; ++row) {
                #pragma unroll
                for (int rr = 0; rr < 3; ++rr) {
                    const float4 u = va[row + rr];
                    const float ux1 = sax[row + rr], uy1 = say[row + rr];
                    const float t0 = wt0[rr * 3], t1_ = wt0[rr * 3 + 1], t2_ = wt0[rr * 3 + 2];
                    if (rr == 0) {
                        pa[row][0] = u.x * t0 + u.y * t1_ + u.z * t2_;
                        pa[row][1] = u.y * t0 + u.z * t1_ + u.w * t2_;
                        pa[row][2] = u.z * t0 + u.w * t1_ + ux1 * t2_;
                        pa[row][3] = u.w * t0 + ux1 * t1_ + uy1 * t2_;
                    } else {
                        pa[row][0] += u.x * t0 + u.y * t1_ + u.z * t2_;
                        pa[row][1] += u.y * t0 + u.z * t1_ + u.w * t2_;
                        pa[row][2] += u.z * t0 + u.w * t1_ + ux1 * t2_;
                        pa[row][3] += u.w * t0 + ux1 * t1_ + uy1 * t2_;
                    }
                }
                #pragma unroll
                for (int rr = 0; rr < 3; ++rr) {
                    const float4 u = vb[row + rr];
                    const float ux1 = sbx[row + rr], uy1 = sby[row + rr];
                    const float t0 = wt1[rr * 3], t1_ = wt1[rr * 3 + 1], t2_ = wt1[rr * 3 + 2];
                    if (rr == 0) {
                        pb[row][0] = u.x * t0 + u.y * t1_ + u.z * t2_;
                        pb[row][1] = u.y * t0 + u.z * t1_ + u.w * t2_;
                        pb[row][2] = u.z * t0 + u.w * t1_ + ux1 * t2_;
                        pb[row][3] = u.w * t0 + ux1 * t1_ + uy1 * t2_;
                    } else {
                        pb[row][0] += u.x * t0 + u.y * t1_ + u.z * t2_;
                        pb[row][1] += u.y * t0 + u.z * t1_ + u.w * t2_;
                        pb[row][2] += u.z * t0 + u.w * t1_ + ux1 * t2_;
                        pb[row][3] += u.w * t0 + ux1 * t1_ + uy1 * t2_;
                    }
                }
            }

            // ---- prefetch next tile: issued here, consumed next iteration.
            //      Latency hides under pack + barrier + MFMA + epilogue.
            float4 na[4], nb[4];
            if (i + 1 < T) {
                const float* p0 = xp0 + ((z + 8 * (i + 1)) * 2) * 64;
                #pragma unroll
                for (int r = 0; r < 4; ++r) na[r] = *(const float4*)(p0 + r * 64);
                #pragma unroll
                for (int r = 0; r < 4; ++r) nb[r] = *(const float4*)(p0 + 4096 + r * 64);
            }

            // ---- pack + LDS write ----
            #pragma unroll
            for (int row = 0; row < 2; ++row) {
                #pragma unroll
                for (int ii = 0; ii < 4; ++ii) {
                    const int pxl = row * 64 + 4 * lm + ii;
                    if (dual) {
                        unsigned H, L;
                        pack2(pa[row][ii], pb[row][ii], H, L);
                        rotH[pxl * 33 + cpair] = H;
                        rotL[pxl * 33 + cpair] = L;
                    } else {
                        rotH[pxl * 33 + cpair] = packH(pa[row][ii], pb[row][ii]);
                    }
                }
            }
            __syncthreads();

            // ---- phase 2: MFMA GEMM, mt-split (acc 16 VGPR live) ----
            #pragma unroll
            for (int mt = 0; mt < 2; ++mt) {
                f32x4 acc[4];
                #pragma unroll
                for (int nt = 0; nt < 4; ++nt) acc[nt] = (f32x4){0.f, 0.f, 0.f, 0.f};

                __builtin_amdgcn_s_setprio(1);
                if (dual) {
                    #pragma unroll
                    for (int nt = 0; nt < 4; ++nt) {
                        #pragma unroll
                        for (int kk = 0; kk < 2; ++kk) {
                            const int idx = (half * 64 + nt * 16 + lm) * 33 + kk * 16 + q * 4;
                            s16x8u bH, bL;
                            #pragma unroll
                            for (int j = 0; j < 4; ++j) bH.u[j] = rotH[idx + j];
                            #pragma unroll
                            for (int j = 0; j < 4; ++j) bL.u[j] = rotL[idx + j];
                            acc[nt] = __builtin_amdgcn_mfma_f32_16x16x32_bf16(aH[mt][kk].v, bH.v, acc[nt], 0, 0, 0);
                            acc[nt] = __builtin_amdgcn_mfma_f32_16x16x32_bf16(aH[mt][kk].v, bL.v, acc[nt], 0, 0, 0);
                            acc[nt] = __builtin_amdgcn_mfma_f32_16x16x32_bf16(aL[mt][kk].v, bH.v, acc[nt], 0, 0, 0);
                        }
                    }
                } else {
                    #pragma unroll
                    for (int nt = 0; nt < 4; ++nt) {
                        #pragma unroll
                        for (int kk = 0; kk < 2; ++kk) {
                            const int idx = (half * 64 + nt * 16 + lm) * 33 + kk * 16 + q * 4;
                            s16x8u bH;
                            #pragma unroll
                            for (int j = 0; j < 4; ++j) bH.u[j] = rotH[idx + j];
                            acc[nt] = __builtin_amdgcn_mfma_f32_16x16x32_bf16(aH[mt][kk].v, bH.v, acc[nt], 0, 0, 0);
                        }
                    }
                }
                __builtin_amdgcn_s_setprio(0);

                // epilogue for this mt: D row = oc (q*4+r), col = nt*16+lm
                const int oc0 = woc + mt * 16 + q * 4;
                #pragma unroll
                for (int nt = 0; nt < 4; ++nt) {
                    const int col = nt * 16 + lm;
                    if (col < 62) {
                        const size_t base =
                            ((size_t)((b * 2 + branch) * 128 + oc0)) * 3844 +
                            (size_t)(h0 + half) * 62 + col;
                        #pragma unroll
                        for (int r = 0; r < 4; ++r) {
                            float v = acc[nt][r];
                            if (dual) v = __expf(v);
                            out[base + (size_t)r * 3844] = v;
                        }
                    }
                }
            }
            __syncthreads();

            // rotate prefetched regs into place
            if (i + 1 < T) {
                #pragma unroll
                for (int r = 0; r < 4; ++r) { va[r] = na[r]; vb[r] = nb[r]; }
            }
        }
    }
}

extern "C" void kernel_launch(void* const* d_in, const int* in_sizes, int n_in,
                              void* d_out, int out_size, void* d_ws, size_t ws_size,
                              hipStream_t stream) {
    const float* x  = (const float*)d_in[0];
    const float* w1 = (const float*)d_in[1];
    const float* w2 = (const float*)d_in[2];
    float* out = (float*)d_out;
    float* ws  = (float*)d_ws;

    prep<<<19, 256, 0, stream>>>(w1, w2, ws);

    dim3 grid(32, 2, 8);
    conv_fused<<<grid, 512, 0, stream>>>(x, ws, out);
}

// Round 3
// 213.438 us; speedup vs baseline: 1.0766x; 1.0766x over previous
//
#include <hip/hip_runtime.h>
#include <cstdint>
#include <cstddef>

#define EPSF 1e-6f

typedef __attribute__((ext_vector_type(4))) float f32x4;
typedef __attribute__((ext_vector_type(8))) short s16x8;
typedef union { s16x8 v; unsigned u[4]; } s16x8u;

// hi/lo dual-bf16 pack via v_cvt_pk_bf16_f32 (1 inst packs 2 floats).
// Residual is computed against the EXACT decode (bf16<<16), so any rounding
// mode in cvt_pk is absorbed by the lo term.
static __device__ __forceinline__ void pack2(float a, float b, unsigned& H, unsigned& L) {
    unsigned h, l;
    asm("v_cvt_pk_bf16_f32 %0, %1, %2" : "=v"(h) : "v"(a), "v"(b));
    float ra = a - __uint_as_float(h << 16);
    float rb = b - __uint_as_float(h & 0xffff0000u);
    asm("v_cvt_pk_bf16_f32 %0, %1, %2" : "=v"(l) : "v"(ra), "v"(rb));
    H = h; L = l;
}
static __device__ __forceinline__ unsigned packH(float a, float b) {
    unsigned h;
    asm("v_cvt_pk_bf16_f32 %0, %1, %2" : "=v"(h) : "v"(a), "v"(b));
    return h;
}

// ws layout (4B units):
//   [0    ..  575]  w1n branch0: [c][9] normalized taps (fp32)
//   [576  .. 1151]  w1n branch1
//   [1152 .. 5247]  w2H branch0 [128][32] u32 c-pair hi
//   [5248 .. 9343]  w2L branch0 [128][32] u32 c-pair lo
//   [9344 ..13439]  w2H branch1
//   [13440..17535]  w2L branch1

__global__ __launch_bounds__(256) void prep(const float* __restrict__ w1,
                                            const float* __restrict__ w2,
                                            float* __restrict__ ws) {
    __shared__ float s1row[64];
    __shared__ float red[4];
    __shared__ float rs8[8];
    const int t = threadIdx.x;
    const int lane = t & 63;
    const int wv = t >> 6;
    const int gid = blockIdx.x * 256 + t;

    // t2 = sum over all 8192 w2^2
    float s = 0.f;
    #pragma unroll
    for (int i = 0; i < 32; ++i) { float v = w2[t + 256 * i]; s += v * v; }
    #pragma unroll
    for (int d = 32; d > 0; d >>= 1) s += __shfl_xor(s, d);
    if (lane == 0) red[wv] = s;

    // w1 row sums (64 rows x 9 taps)
    if (t < 64) {
        float rs = 0.f;
        #pragma unroll
        for (int k = 0; k < 9; ++k) { float v = w1[t * 9 + k]; rs += v * v; }
        s1row[t] = rs;
    }

    // per-row w2 sums for the 8 rows this block packs (blocks 0..15 only)
    if (blockIdx.x < 16) {
        const int r8 = t >> 5;            // 0..7
        const int e = t & 31;
        const int row = blockIdx.x * 8 + r8;
        float v0 = w2[row * 64 + e];
        float v1 = w2[row * 64 + 32 + e];
        float rr = v0 * v0 + v1 * v1;
        #pragma unroll
        for (int d = 16; d > 0; d >>= 1) rr += __shfl_down(rr, d);
        if (e == 0) rs8[r8] = rr;
    }
    __syncthreads();

    const float t2 = red[0] + red[1] + red[2] + red[3];
    float a = s1row[lane];
    #pragma unroll
    for (int d = 32; d > 0; d >>= 1) a += __shfl_xor(a, d);
    const float t1 = a;

    unsigned* wsu = (unsigned*)ws;
    if (gid < 4096) {
        const int row = gid >> 5;
        const int cp = gid & 31;
        float v0 = w2[row * 64 + 2 * cp];
        float v1 = w2[row * 64 + 2 * cp + 1];
        float q0 = v0 * v0, q1 = v1 * v1;
        const float rs = rs8[t >> 5];
        unsigned H, L;
        pack2(q0 / t2, q1 / t2, H, L);
        wsu[1152 + row * 32 + cp] = H;
        wsu[5248 + row * 32 + cp] = L;
        pack2(q0 / rs, q1 / rs, H, L);
        wsu[9344 + row * 32 + cp] = H;
        wsu[13440 + row * 32 + cp] = L;
    } else if (gid < 4672) {
        const int i = gid - 4096;
        const int c = i / 9;
        const int k = i - c * 9;
        float v = w1[i];
        float q = v * v;
        ws[c * 9 + k] = q / t1;
        ws[576 + c * 9 + k] = q / s1row[c];
    }
}

// grid: (32, 2, 31)  block: 512 (8 waves). ONE hg-tile per block (round-1
// structure: 1984 short-lived blocks -> natural cross-block phase diversity).
// NEW vs round 1: register pressure is structurally capped so the kernel fits
// 64 VGPRs (launch_bounds(512,8)) WITHOUT spills -> 4 blocks/CU instead of 1
// (LDS 33 KB x 4 = 132 KB <= 160 KB):
//   - phase 1 runs channel a fully, then channel b (loads for both issued up
//     front; shuffle/FMA state sequenced, peak ~56 regs)
//   - aH loaded after the pack (pa/pb dead there), aL per-mt inside phase 2
//   - phase 2 mt-split: only 16 acc regs live, epilogue per mt
// Branch 0 (rot): single bf16 term (outputs O(1e-4), abs err ~2e-7).
// Branch 1 (abs/exp): 3-term hi/lo split (AhBh + AhBl + AlBh).
__global__ __launch_bounds__(512, 8) void conv_fused(const float* __restrict__ x,
                                                     const float* __restrict__ ws,
                                                     float* __restrict__ out) {
    const int b = blockIdx.x;
    const int branch = blockIdx.y;
    const int hg = blockIdx.z;
    const int h0 = hg * 2;
    const int t = threadIdx.x;
    const int lane = t & 63;
    const int w = __builtin_amdgcn_readfirstlane(t >> 6);
    const int lm = lane & 15;
    const int q = lane >> 4;
    const bool dual = (branch != 0);

    __shared__ unsigned rotH[128 * 33];
    __shared__ unsigned rotL[128 * 33];

    const float* __restrict__ w1n = ws + branch * 576;
    const unsigned* __restrict__ wsu = (const unsigned*)ws;
    const unsigned* __restrict__ w2H = wsu + 1152 + branch * 8192;
    const unsigned* __restrict__ w2L = w2H + 4096;
    const float* __restrict__ xb = x + (size_t)(b * 2 + branch) * (64 * 4096);

    const int woc = (w & 3) * 32;
    const int half = w >> 2;
    const int cpair = w * 4 + q;
    const int c0 = 2 * cpair;

    // ---- phase 1: depthwise 3x3 on 2 channels, 2 output rows ----
    {
        const float* xp0 = xb + c0 * 4096 + h0 * 64 + 4 * lm;
        float4 va[4], vb[4];
        #pragma unroll
        for (int r = 0; r < 4; ++r) va[r] = *(const float4*)(xp0 + r * 64);
        #pragma unroll
        for (int r = 0; r < 4; ++r) vb[r] = *(const float4*)(xp0 + 4096 + r * 64);

        const float* wc0 = w1n + c0 * 9;
        float pa[2][4], pb[2][4];

        // ---- channel a ----
        if (dual) {
            #pragma unroll
            for (int r = 0; r < 4; ++r) {
                va[r].x = __logf(va[r].x + EPSF); va[r].y = __logf(va[r].y + EPSF);
                va[r].z = __logf(va[r].z + EPSF); va[r].w = __logf(va[r].w + EPSF);
            }
        }
        {
            float sax[4], say[4];
            #pragma unroll
            for (int r = 0; r < 4; ++r) {
                sax[r] = __shfl_down(va[r].x, 1); say[r] = __shfl_down(va[r].y, 1);
            }
            #pragma unroll
            for (int row = 0; row < 2; ++row) {
                #pragma unroll
                for (int rr = 0; rr < 3; ++rr) {
                    const float4 u = va[row + rr];
                    const float ux1 = sax[row + rr], uy1 = say[row + rr];
                    const float t0 = wc0[rr * 3], t1_ = wc0[rr * 3 + 1], t2_ = wc0[rr * 3 + 2];
                    if (rr == 0) {
                        pa[row][0] = u.x * t0 + u.y * t1_ + u.z * t2_;
                        pa[row][1] = u.y * t0 + u.z * t1_ + u.w * t2_;
                        pa[row][2] = u.z * t0 + u.w * t1_ + ux1 * t2_;
                        pa[row][3] = u.w * t0 + ux1 * t1_ + uy1 * t2_;
                    } else {
                        pa[row][0] += u.x * t0 + u.y * t1_ + u.z * t2_;
                        pa[row][1] += u.y * t0 + u.z * t1_ + u.w * t2_;
                        pa[row][2] += u.z * t0 + u.w * t1_ + ux1 * t2_;
                        pa[row][3] += u.w * t0 + ux1 * t1_ + uy1 * t2_;
                    }
                }
            }
        }

        // ---- channel b ----
        if (dual) {
            #pragma unroll
            for (int r = 0; r < 4; ++r) {
                vb[r].x = __logf(vb[r].x + EPSF); vb[r].y = __logf(vb[r].y + EPSF);
                vb[r].z = __logf(vb[r].z + EPSF); vb[r].w = __logf(vb[r].w + EPSF);
            }
        }
        {
            const float* wc1 = wc0 + 9;
            float sbx[4], sby[4];
            #pragma unroll
            for (int r = 0; r < 4; ++r) {
                sbx[r] = __shfl_down(vb[r].x, 1); sby[r] = __shfl_down(vb[r].y, 1);
            }
            #pragma unroll
            for (int row = 0; row < 2; ++row) {
                #pragma unroll
                for (int rr = 0; rr < 3; ++rr) {
                    const float4 u = vb[row + rr];
                    const float ux1 = sbx[row + rr], uy1 = sby[row + rr];
                    const float t0 = wc1[rr * 3], t1_ = wc1[rr * 3 + 1], t2_ = wc1[rr * 3 + 2];
                    if (rr == 0) {
                        pb[row][0] = u.x * t0 + u.y * t1_ + u.z * t2_;
                        pb[row][1] = u.y * t0 + u.z * t1_ + u.w * t2_;
                        pb[row][2] = u.z * t0 + u.w * t1_ + ux1 * t2_;
                        pb[row][3] = u.w * t0 + ux1 * t1_ + uy1 * t2_;
                    } else {
                        pb[row][0] += u.x * t0 + u.y * t1_ + u.z * t2_;
                        pb[row][1] += u.y * t0 + u.z * t1_ + u.w * t2_;
                        pb[row][2] += u.z * t0 + u.w * t1_ + ux1 * t2_;
                        pb[row][3] += u.w * t0 + ux1 * t1_ + uy1 * t2_;
                    }
                }
            }
        }

        // ---- pack + LDS write ----
        #pragma unroll
        for (int row = 0; row < 2; ++row) {
            #pragma unroll
            for (int ii = 0; ii < 4; ++ii) {
                const int pxl = row * 64 + 4 * lm + ii;
                if (dual) {
                    unsigned H, L;
                    pack2(pa[row][ii], pb[row][ii], H, L);
                    rotH[pxl * 33 + cpair] = H;
                    rotL[pxl * 33 + cpair] = L;
                } else {
                    rotH[pxl * 33 + cpair] = packH(pa[row][ii], pb[row][ii]);
                }
            }
        }
    }

    // ---- aH loads here: pa/pb dead, latency hides under the barrier ----
    s16x8u aH[2][2];
    #pragma unroll
    for (int mt = 0; mt < 2; ++mt) {
        #pragma unroll
        for (int kk = 0; kk < 2; ++kk) {
            const int off = (woc + mt * 16 + lm) * 32 + kk * 16 + q * 4;
            #pragma unroll
            for (int j = 0; j < 4; ++j) aH[mt][kk].u[j] = w2H[off + j];
        }
    }
    __syncthreads();

    // ---- phase 2: MFMA GEMM, mt-split (acc 16 VGPR live), aL per-mt ----
    #pragma unroll
    for (int mt = 0; mt < 2; ++mt) {
        f32x4 acc[4];
        #pragma unroll
        for (int nt = 0; nt < 4; ++nt) acc[nt] = (f32x4){0.f, 0.f, 0.f, 0.f};

        if (dual) {
            s16x8u aL[2];
            #pragma unroll
            for (int kk = 0; kk < 2; ++kk) {
                const int off = (woc + mt * 16 + lm) * 32 + kk * 16 + q * 4;
                #pragma unroll
                for (int j = 0; j < 4; ++j) aL[kk].u[j] = w2L[off + j];
            }
            __builtin_amdgcn_s_setprio(1);
            #pragma unroll
            for (int nt = 0; nt < 4; ++nt) {
                #pragma unroll
                for (int kk = 0; kk < 2; ++kk) {
                    const int idx = (half * 64 + nt * 16 + lm) * 33 + kk * 16 + q * 4;
                    s16x8u bH, bL;
                    #pragma unroll
                    for (int j = 0; j < 4; ++j) bH.u[j] = rotH[idx + j];
                    #pragma unroll
                    for (int j = 0; j < 4; ++j) bL.u[j] = rotL[idx + j];
                    acc[nt] = __builtin_amdgcn_mfma_f32_16x16x32_bf16(aH[mt][kk].v, bH.v, acc[nt], 0, 0, 0);
                    acc[nt] = __builtin_amdgcn_mfma_f32_16x16x32_bf16(aH[mt][kk].v, bL.v, acc[nt], 0, 0, 0);
                    acc[nt] = __builtin_amdgcn_mfma_f32_16x16x32_bf16(aL[kk].v, bH.v, acc[nt], 0, 0, 0);
                }
            }
            __builtin_amdgcn_s_setprio(0);
        } else {
            __builtin_amdgcn_s_setprio(1);
            #pragma unroll
            for (int nt = 0; nt < 4; ++nt) {
                #pragma unroll
                for (int kk = 0; kk < 2; ++kk) {
                    const int idx = (half * 64 + nt * 16 + lm) * 33 + kk * 16 + q * 4;
                    s16x8u bH;
                    #pragma unroll
                    for (int j = 0; j < 4; ++j) bH.u[j] = rotH[idx + j];
                    acc[nt] = __builtin_amdgcn_mfma_f32_16x16x32_bf16(aH[mt][kk].v, bH.v, acc[nt], 0, 0, 0);
                }
            }
            __builtin_amdgcn_s_setprio(0);
        }

        // ---- epilogue for this mt: D row = oc (q*4+r), col = nt*16+lm ----
        const int oc0 = woc + mt * 16 + q * 4;
        #pragma unroll
        for (int nt = 0; nt < 4; ++nt) {
            const int col = nt * 16 + lm;
            if (col < 62) {
                const size_t base =
                    ((size_t)((b * 2 + branch) * 128 + oc0)) * 3844 +
                    (size_t)(h0 + half) * 62 + col;
                #pragma unroll
                for (int r = 0; r < 4; ++r) {
                    float v = acc[nt][r];
                    if (dual) v = __expf(v);
                    out[base + (size_t)r * 3844] = v;
                }
            }
        }
    }
}

extern "C" void kernel_launch(void* const* d_in, const int* in_sizes, int n_in,
                              void* d_out, int out_size, void* d_ws, size_t ws_size,
                              hipStream_t stream) {
    const float* x  = (const float*)d_in[0];
    const float* w1 = (const float*)d_in[1];
    const float* w2 = (const float*)d_in[2];
    float* out = (float*)d_out;
    float* ws  = (float*)d_ws;

    prep<<<19, 256, 0, stream>>>(w1, w2, ws);

    dim3 grid(32, 2, 31);
    conv_fused<<<grid, 512, 0, stream>>>(x, ws, out);
}